// Round 1
// baseline (22663.986 us; speedup 1.0000x reference)
//
#include <hip/hip_runtime.h>
#include <math.h>

constexpr int Bb  = 64;
constexpr int Tt  = 2048;
constexpr int INN = 128;
constexpr int HH  = 256;
constexpr int ROWS = Bb * Tt;   // 131072

// ---------------------------------------------------------------------------
// GEMM: out[row][j] = sum_k in[row][k] * W[j][k] + bias1[j] + bias2[j]
// rows = B*T, j < 256, K in {128, 256}. Tile: 64 rows x 256 cols, Kc=16,
// 256 threads, 8x8 register tile per thread.
// In-place safe when in == out: a WG reads its 64 rows fully (all K) inside
// the k-loop and only writes those same rows in the epilogue; it owns ALL
// 256 output cols of those rows, so no cross-WG hazard.
// ---------------------------------------------------------------------------
template <int K>
__global__ __launch_bounds__(256) void ih_gemm(const float* in, const float* W,
                                               const float* bias1, const float* bias2,
                                               float* out)
{
    __shared__ float a_lds[16][68];    // [kk][row]   (+4 pad)
    __shared__ float b_lds[16][264];   // [kk][col]   (+8 pad)

    const int tid = threadIdx.x;
    const int tx  = tid & 31;   // col group: cols tx*8 .. +8
    const int ty  = tid >> 5;   // row group: rows ty*8 .. +8
    const int row0 = blockIdx.x * 64;

    float acc[8][8];
#pragma unroll
    for (int r = 0; r < 8; ++r)
#pragma unroll
        for (int c = 0; c < 8; ++c) acc[r][c] = 0.f;

    for (int k0 = 0; k0 < K; k0 += 16) {
        // stage A tile: 64 rows x 16 k  (1024 elems, 4 per thread)
#pragma unroll
        for (int i = 0; i < 4; ++i) {
            int e = i * 256 + tid;
            int r = e >> 4, kk = e & 15;
            a_lds[kk][r] = in[(row0 + r) * K + k0 + kk];
        }
        // stage B tile: 256 cols x 16 k (4096 elems, 16 per thread)
#pragma unroll
        for (int i = 0; i < 16; ++i) {
            int e = i * 256 + tid;
            int j = e >> 4, kk = e & 15;
            b_lds[kk][j] = W[j * K + k0 + kk];
        }
        __syncthreads();

#pragma unroll
        for (int kk = 0; kk < 16; ++kk) {
            float4 a0 = *(const float4*)&a_lds[kk][ty * 8];
            float4 a1 = *(const float4*)&a_lds[kk][ty * 8 + 4];
            float4 b0 = *(const float4*)&b_lds[kk][tx * 8];
            float4 b1 = *(const float4*)&b_lds[kk][tx * 8 + 4];
            float av[8] = {a0.x, a0.y, a0.z, a0.w, a1.x, a1.y, a1.z, a1.w};
            float bv[8] = {b0.x, b0.y, b0.z, b0.w, b1.x, b1.y, b1.z, b1.w};
#pragma unroll
            for (int r = 0; r < 8; ++r)
#pragma unroll
                for (int c = 0; c < 8; ++c)
                    acc[r][c] += av[r] * bv[c];
        }
        __syncthreads();
    }

    // epilogue: add biases, write 8x8 tile
    float bsum[8];
#pragma unroll
    for (int c = 0; c < 8; ++c) {
        int j = tx * 8 + c;
        bsum[c] = bias1[j] + bias2[j];
    }
#pragma unroll
    for (int r = 0; r < 8; ++r) {
        int row = row0 + ty * 8 + r;
        float4 o0 = make_float4(acc[r][0] + bsum[0], acc[r][1] + bsum[1],
                                acc[r][2] + bsum[2], acc[r][3] + bsum[3]);
        float4 o1 = make_float4(acc[r][4] + bsum[4], acc[r][5] + bsum[5],
                                acc[r][6] + bsum[6], acc[r][7] + bsum[7]);
        *(float4*)&out[row * HH + tx * 8]     = o0;
        *(float4*)&out[row * HH + tx * 8 + 4] = o1;
    }
}

// ---------------------------------------------------------------------------
// fast tanh: (e^{2x}-1)/(e^{2x}+1) via native v_exp_f32 + v_rcp_f32.
// |error| ~1e-7 absolute vs libm tanhf; inputs clamped so exp2 arg <= 26.
// ---------------------------------------------------------------------------
__device__ __forceinline__ float fast_tanh(float x)
{
    float xc = fmaxf(-9.0f, fminf(9.0f, x));          // tanh(9) = 1 - 2.4e-8
    float e  = __expf(2.0f * xc);                     // native: v_exp_f32
    return (e - 1.0f) * __builtin_amdgcn_rcpf(e + 1.0f);
}

// ---------------------------------------------------------------------------
// Recurrence v2: in-place over xp:  h_t = tanh(xp[t] + W_hh @ h_{t-1}),
// xp[b][t][:] overwritten with h_t. One WG per batch, 1024 threads (16 waves).
//
// Design (LDS-pipe minimization vs v1):
//  - wave w owns k-chunk [16w,16w+16).  h_{t-1} chunk enters the wave as
//    SGPRs: one lane-spread ds_read_b32 + 16 v_readlane (no wave-wide
//    uniform b128 gather -> LDS gather cost 16x5.8 cyc instead of 768).
//  - lane l owns outputs {l, 64+l, 128+l, 192+l}; per-step partials are
//    accumulated into a double-buffered LDS accumulator via ds_add_f32
//    atomics (addr stride 64 words -> 2-way bank aliasing = free). This
//    replaces the write-partials + serial-reduce-phase + 2nd barrier.
//  - wave w tanh-finishes its own chunk (accum + prefetched xp), writes h
//    directly to global; h never round-trips through LDS.
//  - ONE __syncthreads per step (publishes this step's atomics, orders the
//    consumed buffer's zeroing against next step's atomics).
// Buffer protocol: step t reads cur=acc[t&1] (completed matvec of h_{t-1}),
// zeroes its own chunk of cur after reading, atomically adds W@h_t into
// nxt=acc[(t+1)&1]. Both buffers zeroed before t=0 (h_{-1}=0).
// ---------------------------------------------------------------------------
__device__ __forceinline__ void rnn_step(float* cur, float* nxt, int t,
                                         float& xg, float* xpb,
                                         const float (&wreg)[4][16],
                                         int l, int cidx)
{
    // (A) prefetch next step's xp value (full-step latency hiding).
    //     Last-step clamp re-reads row Tt-1 (value never consumed; the
    //     program-order store below is same-thread, so no hazard matters).
    int tn = (t + 1 < Tt) ? t + 1 : Tt - 1;
    float xg2 = xpb[(size_t)tn * HH + cidx];

    // (B) finish my chunk: accum + xp, tanh. Lanes 16..63 replicate lanes
    //     0..15 (same cidx) -> broadcast read, no conflict, no divergence.
    float a  = cur[cidx];
    float hv = fast_tanh(a + xg);

    // (C) commit h to global (in-place over xp[t], already consumed) and
    //     zero the consumed accumulator chunk for reuse at step t+1.
    if (l < 16) {
        xpb[(size_t)t * HH + cidx] = hv;
        cur[cidx] = 0.f;
    }

    // (D) broadcast h chunk to SGPRs: lane c (c<16) holds h[16w+c].
    float hc[16];
#pragma unroll
    for (int c = 0; c < 16; ++c)
        hc[c] = __int_as_float(__builtin_amdgcn_readlane(__float_as_int(hv), c));

    // (E) matvec partials: p_r = sum_c Whh[64r+l][16w+c] * h[16w+c]
    float p0 = 0.f, p1 = 0.f, p2 = 0.f, p3 = 0.f;
#pragma unroll
    for (int c = 0; c < 16; ++c) {
        p0 = fmaf(wreg[0][c], hc[c], p0);
        p1 = fmaf(wreg[1][c], hc[c], p1);
        p2 = fmaf(wreg[2][c], hc[c], p2);
        p3 = fmaf(wreg[3][c], hc[c], p3);
    }

    // (F) reduce across the 16 waves: LDS float atomics. Word addresses
    //     l + 64r: lanes l and l+32 share a bank (2-way, free per m136).
    __hip_atomic_fetch_add(&nxt[l],       p0, __ATOMIC_RELAXED, __HIP_MEMORY_SCOPE_WORKGROUP);
    __hip_atomic_fetch_add(&nxt[64 + l],  p1, __ATOMIC_RELAXED, __HIP_MEMORY_SCOPE_WORKGROUP);
    __hip_atomic_fetch_add(&nxt[128 + l], p2, __ATOMIC_RELAXED, __HIP_MEMORY_SCOPE_WORKGROUP);
    __hip_atomic_fetch_add(&nxt[192 + l], p3, __ATOMIC_RELAXED, __HIP_MEMORY_SCOPE_WORKGROUP);

    __syncthreads();   // publishes atomics of step t; orders cur-zeroing
                       // against step t+1's atomics into the same buffer
    xg = xg2;
}

__global__ __launch_bounds__(1024) void rnn_recur(float* xp, const float* Whh)
{
    __shared__ float accA[HH];
    __shared__ float accB[HH];

    const int tid  = threadIdx.x;
    const int w    = tid >> 6;          // wave 0..15 -> k-chunk [16w,16w+16)
    const int l    = tid & 63;
    const int cidx = 16 * w + (l & 15); // my chunk element (x4 replicated)
    float* xpb = xp + (size_t)blockIdx.x * Tt * HH;

    // weights (one-time): wreg[r][c] = Whh[(64r + l)][16w + c]
    float wreg[4][16];
#pragma unroll
    for (int r = 0; r < 4; ++r) {
        const float4* wp = (const float4*)&Whh[(size_t)(64 * r + l) * HH + 16 * w];
#pragma unroll
        for (int q = 0; q < 4; ++q) {
            float4 v = wp[q];
            wreg[r][4 * q + 0] = v.x;
            wreg[r][4 * q + 1] = v.y;
            wreg[r][4 * q + 2] = v.z;
            wreg[r][4 * q + 3] = v.w;
        }
    }

    if (tid < HH) { accA[tid] = 0.f; accB[tid] = 0.f; }   // h_{-1} = 0
    float xg = xpb[cidx];                                 // xp[t=0]
    __syncthreads();

#pragma unroll 1
    for (int t = 0; t < Tt; t += 2) {     // Tt even: explicit buffer swap
        rnn_step(accA, accB, t,     xg, xpb, wreg, l, cidx);
        rnn_step(accB, accA, t + 1, xg, xpb, wreg, l, cidx);
    }
}

// ---------------------------------------------------------------------------
// FC: out[b] = dot(h2[b][T-1][:], W_fc) + b_fc.  One wave per batch.
// ---------------------------------------------------------------------------
__global__ __launch_bounds__(64) void fc_kernel(const float* h2, const float* Wfc,
                                                const float* bfc, float* out)
{
    const int b = blockIdx.x;
    const int l = threadIdx.x;    // 0..63
    const float* hrow = h2 + ((size_t)b * Tt + (Tt - 1)) * HH;
    float4 hv = *(const float4*)&hrow[4 * l];
    float4 wv = *(const float4*)&Wfc[4 * l];
    float p = hv.x * wv.x + hv.y * wv.y + hv.z * wv.z + hv.w * wv.w;
#pragma unroll
    for (int off = 32; off > 0; off >>= 1) p += __shfl_down(p, off, 64);
    if (l == 0) out[b] = p + bfc[0];
}

// ---------------------------------------------------------------------------
extern "C" void kernel_launch(void* const* d_in, const int* in_sizes, int n_in,
                              void* d_out, int out_size, void* d_ws, size_t ws_size,
                              hipStream_t stream)
{
    const float* x     = (const float*)d_in[0];
    const float* W_ih0 = (const float*)d_in[1];
    const float* W_hh0 = (const float*)d_in[2];
    const float* b_ih0 = (const float*)d_in[3];
    const float* b_hh0 = (const float*)d_in[4];
    const float* W_ih1 = (const float*)d_in[5];
    const float* W_hh1 = (const float*)d_in[6];
    const float* b_ih1 = (const float*)d_in[7];
    const float* b_hh1 = (const float*)d_in[8];
    const float* W_fc  = (const float*)d_in[9];
    const float* b_fc  = (const float*)d_in[10];
    float* ws  = (float*)d_ws;                 // B*T*H floats (128 MiB)
    float* out = (float*)d_out;                // 64 floats

    // 1) xp0 = x @ W_ih0^T + b_ih0 + b_hh0
    ih_gemm<INN><<<ROWS / 64, 256, 0, stream>>>(x, W_ih0, b_ih0, b_hh0, ws);
    // 2) layer-0 recurrence (in-place: ws becomes h1 sequence)
    rnn_recur<<<Bb, 1024, 0, stream>>>(ws, W_hh0);
    // 3) xp1 = h1 @ W_ih1^T + b_ih1 + b_hh1   (in-place)
    ih_gemm<HH><<<ROWS / 64, 256, 0, stream>>>(ws, W_ih1, b_ih1, b_hh1, ws);
    // 4) layer-1 recurrence (in-place: ws becomes h2 sequence)
    rnn_recur<<<Bb, 1024, 0, stream>>>(ws, W_hh1);
    // 5) out = h2[:, T-1, :] @ W_fc^T + b_fc
    fc_kernel<<<Bb, 64, 0, stream>>>(ws, W_fc, b_fc, out);
}

// Round 2
// 3147.278 us; speedup vs baseline: 7.2011x; 7.2011x over previous
//
#include <hip/hip_runtime.h>
#include <math.h>

constexpr int Bb  = 64;
constexpr int Tt  = 2048;
constexpr int INN = 128;
constexpr int HH  = 256;
constexpr int ROWS = Bb * Tt;   // 131072

// ---------------------------------------------------------------------------
// GEMM: out[row][j] = sum_k in[row][k] * W[j][k] + bias1[j] + bias2[j]
// rows = B*T, j < 256, K in {128, 256}. Tile: 64 rows x 256 cols, Kc=16,
// 256 threads, 8x8 register tile per thread.
// In-place safe when in == out (WG owns all 256 cols of its 64 rows).
// ---------------------------------------------------------------------------
template <int K>
__global__ __launch_bounds__(256) void ih_gemm(const float* in, const float* W,
                                               const float* bias1, const float* bias2,
                                               float* out)
{
    __shared__ float a_lds[16][68];    // [kk][row]   (+4 pad)
    __shared__ float b_lds[16][264];   // [kk][col]   (+8 pad)

    const int tid = threadIdx.x;
    const int tx  = tid & 31;   // col group: cols tx*8 .. +8
    const int ty  = tid >> 5;   // row group: rows ty*8 .. +8
    const int row0 = blockIdx.x * 64;

    float acc[8][8];
#pragma unroll
    for (int r = 0; r < 8; ++r)
#pragma unroll
        for (int c = 0; c < 8; ++c) acc[r][c] = 0.f;

    for (int k0 = 0; k0 < K; k0 += 16) {
#pragma unroll
        for (int i = 0; i < 4; ++i) {
            int e = i * 256 + tid;
            int r = e >> 4, kk = e & 15;
            a_lds[kk][r] = in[(row0 + r) * K + k0 + kk];
        }
#pragma unroll
        for (int i = 0; i < 16; ++i) {
            int e = i * 256 + tid;
            int j = e >> 4, kk = e & 15;
            b_lds[kk][j] = W[j * K + k0 + kk];
        }
        __syncthreads();

#pragma unroll
        for (int kk = 0; kk < 16; ++kk) {
            float4 a0 = *(const float4*)&a_lds[kk][ty * 8];
            float4 a1 = *(const float4*)&a_lds[kk][ty * 8 + 4];
            float4 b0 = *(const float4*)&b_lds[kk][tx * 8];
            float4 b1 = *(const float4*)&b_lds[kk][tx * 8 + 4];
            float av[8] = {a0.x, a0.y, a0.z, a0.w, a1.x, a1.y, a1.z, a1.w};
            float bv[8] = {b0.x, b0.y, b0.z, b0.w, b1.x, b1.y, b1.z, b1.w};
#pragma unroll
            for (int r = 0; r < 8; ++r)
#pragma unroll
                for (int c = 0; c < 8; ++c)
                    acc[r][c] += av[r] * bv[c];
        }
        __syncthreads();
    }

    float bsum[8];
#pragma unroll
    for (int c = 0; c < 8; ++c) {
        int j = tx * 8 + c;
        bsum[c] = bias1[j] + bias2[j];
    }
#pragma unroll
    for (int r = 0; r < 8; ++r) {
        int row = row0 + ty * 8 + r;
        float4 o0 = make_float4(acc[r][0] + bsum[0], acc[r][1] + bsum[1],
                                acc[r][2] + bsum[2], acc[r][3] + bsum[3]);
        float4 o1 = make_float4(acc[r][4] + bsum[4], acc[r][5] + bsum[5],
                                acc[r][6] + bsum[6], acc[r][7] + bsum[7]);
        *(float4*)&out[row * HH + tx * 8]     = o0;
        *(float4*)&out[row * HH + tx * 8 + 4] = o1;
    }
}

// ---------------------------------------------------------------------------
// fast tanh: (e^{2x}-1)/(e^{2x}+1) via native v_exp_f32 + v_rcp_f32.
// ---------------------------------------------------------------------------
__device__ __forceinline__ float fast_tanh(float x)
{
    float xc = fmaxf(-9.0f, fminf(9.0f, x));          // tanh(9) = 1 - 2.4e-8
    float e  = __expf(2.0f * xc);                     // native: v_exp_f32
    return (e - 1.0f) * __builtin_amdgcn_rcpf(e + 1.0f);
}

// ---------------------------------------------------------------------------
// Recurrence v3: h_t = tanh(xp[t] + W_hh @ h_{t-1}), in-place over xp.
// One WG (16 waves, 1024 thr) per batch.
//
// Dataflow per step (ONE barrier, NO atomics, NO serial phase):
//   - wave w owns k-chunk [16w,16w+16); lane l owns outputs 4l..4l+3.
//     wreg[r][c] = Whh[(4l+r)*H + 16w+c] held in 64 VGPRs (one-time load).
//   - h chunk enters the wave as SGPRs via v_readlane of the wave's OWN
//     finish result (h never round-trips LDS).
//   - partials: p_r = sum_c wreg[r][c]*h[16w+c]; one ds_write_b128 per wave
//     into double-buffered pbuf[nxt] (contiguous 256 words, conflict-free).
//   - barrier.
//   - distributed reduce (all 16 waves): wave w finishes outputs
//     j = 16w+(l&15); lane group g = l>>4 reads partial vectors 4g..4g+3
//     (4x ds_read_b32, bank pattern = exactly 2-way aliasing = free), then
//     2x shfl_xor (16, 32) folds the 4 groups; + xp, tanh; lanes<16 commit
//     h to global. Result (replicated x4) feeds next step's readlane.
// Buffer protocol: step t reads pbuf[t&1], writes pbuf[(t+1)&1]. Single
// barrier per step is safe: reads of buf X (step t) precede the step-t
// barrier in program order; writes of buf X (step t+1) follow it.
// ---------------------------------------------------------------------------
constexpr int PS = HH + 4;   // 260; (4g+q)*260 mod 32 spreads groups 16 apart

__global__ __launch_bounds__(1024) void rnn_recur(float* xp, const float* Whh)
{
    __shared__ float pbuf[2][16 * PS];   // 2 x 16.6 KB

    const int tid = threadIdx.x;
    const int w   = tid >> 6;            // wave 0..15 -> k-chunk [16w,16w+16)
    const int l   = tid & 63;
    const int g   = l >> 4;              // reduce lane-group 0..3
    const int jr  = 16 * w + (l & 15);   // output index this lane finishes
    float* xpb = xp + (size_t)blockIdx.x * Tt * HH;

    // weights (one-time): wreg[r][c] = Whh[(4l + r)][16w + c]
    float wreg[4][16];
#pragma unroll
    for (int r = 0; r < 4; ++r) {
        const float4* wp = (const float4*)&Whh[(size_t)(4 * l + r) * HH + 16 * w];
#pragma unroll
        for (int q = 0; q < 4; ++q) {
            float4 v = wp[q];
            wreg[r][4 * q + 0] = v.x;
            wreg[r][4 * q + 1] = v.y;
            wreg[r][4 * q + 2] = v.z;
            wreg[r][4 * q + 3] = v.w;
        }
    }

    // prologue: h_{-1} = 0 -> step-0 partials are all zero
    *(float4*)&pbuf[0][w * PS + 4 * l] = make_float4(0.f, 0.f, 0.f, 0.f);
    float xg = xpb[jr];                  // xp[t=0][jr] (replicated x4)
    __syncthreads();

#pragma unroll 1
    for (int t = 0; t < Tt; ++t) {
        const int cb = t & 1;

        // (A) prefetch next step's xp value (hidden under this step)
        int tn = (t + 1 < Tt) ? t + 1 : Tt - 1;
        float xg2 = xpb[(size_t)tn * HH + jr];

        // (B) distributed reduce of last step's partials for output jr
        const float* pc = &pbuf[cb][4 * g * PS + jr];
        float s0 = pc[0 * PS], s1 = pc[1 * PS], s2 = pc[2 * PS], s3 = pc[3 * PS];
        float s = (s0 + s1) + (s2 + s3);
        s += __shfl_xor(s, 16, 64);      // fold groups g ^ 1
        s += __shfl_xor(s, 32, 64);      // fold groups g ^ 2

        // (C) finish: tanh, commit h (lanes 0..15; others replicate)
        float hv = fast_tanh(s + xg);
        if (l < 16) xpb[(size_t)t * HH + jr] = hv;

        // (D) broadcast my wave's h chunk into SGPRs
        float hc[16];
#pragma unroll
        for (int c = 0; c < 16; ++c)
            hc[c] = __int_as_float(__builtin_amdgcn_readlane(__float_as_int(hv), c));

        // (E) partials of W_hh @ h_t for next step
        float p0 = 0.f, p1 = 0.f, p2 = 0.f, p3 = 0.f;
#pragma unroll
        for (int c = 0; c < 16; ++c) {
            p0 = fmaf(wreg[0][c], hc[c], p0);
            p1 = fmaf(wreg[1][c], hc[c], p1);
            p2 = fmaf(wreg[2][c], hc[c], p2);
            p3 = fmaf(wreg[3][c], hc[c], p3);
        }

        // (F) one contiguous b128 write into the other buffer
        *(float4*)&pbuf[cb ^ 1][w * PS + 4 * l] = make_float4(p0, p1, p2, p3);

        __syncthreads();
        xg = xg2;
    }
}

// ---------------------------------------------------------------------------
// FC: out[b] = dot(h2[b][T-1][:], W_fc) + b_fc.  One wave per batch.
// ---------------------------------------------------------------------------
__global__ __launch_bounds__(64) void fc_kernel(const float* h2, const float* Wfc,
                                                const float* bfc, float* out)
{
    const int b = blockIdx.x;
    const int l = threadIdx.x;    // 0..63
    const float* hrow = h2 + ((size_t)b * Tt + (Tt - 1)) * HH;
    float4 hv = *(const float4*)&hrow[4 * l];
    float4 wv = *(const float4*)&Wfc[4 * l];
    float p = hv.x * wv.x + hv.y * wv.y + hv.z * wv.z + hv.w * wv.w;
#pragma unroll
    for (int off = 32; off > 0; off >>= 1) p += __shfl_down(p, off, 64);
    if (l == 0) out[b] = p + bfc[0];
}

// ---------------------------------------------------------------------------
extern "C" void kernel_launch(void* const* d_in, const int* in_sizes, int n_in,
                              void* d_out, int out_size, void* d_ws, size_t ws_size,
                              hipStream_t stream)
{
    const float* x     = (const float*)d_in[0];
    const float* W_ih0 = (const float*)d_in[1];
    const float* W_hh0 = (const float*)d_in[2];
    const float* b_ih0 = (const float*)d_in[3];
    const float* b_hh0 = (const float*)d_in[4];
    const float* W_ih1 = (const float*)d_in[5];
    const float* W_hh1 = (const float*)d_in[6];
    const float* b_ih1 = (const float*)d_in[7];
    const float* b_hh1 = (const float*)d_in[8];
    const float* W_fc  = (const float*)d_in[9];
    const float* b_fc  = (const float*)d_in[10];
    float* ws  = (float*)d_ws;                 // B*T*H floats (128 MiB)
    float* out = (float*)d_out;                // 64 floats

    // 1) xp0 = x @ W_ih0^T + b_ih0 + b_hh0
    ih_gemm<INN><<<ROWS / 64, 256, 0, stream>>>(x, W_ih0, b_ih0, b_hh0, ws);
    // 2) layer-0 recurrence (in-place: ws becomes h1 sequence)
    rnn_recur<<<Bb, 1024, 0, stream>>>(ws, W_hh0);
    // 3) xp1 = h1 @ W_ih1^T + b_ih1 + b_hh1   (in-place)
    ih_gemm<HH><<<ROWS / 64, 256, 0, stream>>>(ws, W_ih1, b_ih1, b_hh1, ws);
    // 4) layer-1 recurrence (in-place: ws becomes h2 sequence)
    rnn_recur<<<Bb, 1024, 0, stream>>>(ws, W_hh1);
    // 5) out = h2[:, T-1, :] @ W_fc^T + b_fc
    fc_kernel<<<Bb, 64, 0, stream>>>(ws, W_fc, b_fc, out);
}

// Round 3
// 2750.178 us; speedup vs baseline: 8.2409x; 1.1444x over previous
//
#include <hip/hip_runtime.h>
#include <math.h>

constexpr int Bb  = 64;
constexpr int Tt  = 2048;
constexpr int INN = 128;
constexpr int HH  = 256;
constexpr int ROWS = Bb * Tt;   // 131072

// ---------------------------------------------------------------------------
// GEMM: out[row][j] = sum_k in[row][k] * W[j][k] + bias1[j] + bias2[j]
// rows = B*T, j < 256, K in {128, 256}. Tile: 64 rows x 256 cols, Kc=16,
// 256 threads, 8x8 register tile per thread.
// In-place safe when in == out (WG owns all 256 cols of its 64 rows).
// ---------------------------------------------------------------------------
template <int K>
__global__ __launch_bounds__(256) void ih_gemm(const float* in, const float* W,
                                               const float* bias1, const float* bias2,
                                               float* out)
{
    __shared__ float a_lds[16][68];    // [kk][row]   (+4 pad)
    __shared__ float b_lds[16][264];   // [kk][col]   (+8 pad)

    const int tid = threadIdx.x;
    const int tx  = tid & 31;   // col group: cols tx*8 .. +8
    const int ty  = tid >> 5;   // row group: rows ty*8 .. +8
    const int row0 = blockIdx.x * 64;

    float acc[8][8];
#pragma unroll
    for (int r = 0; r < 8; ++r)
#pragma unroll
        for (int c = 0; c < 8; ++c) acc[r][c] = 0.f;

    for (int k0 = 0; k0 < K; k0 += 16) {
#pragma unroll
        for (int i = 0; i < 4; ++i) {
            int e = i * 256 + tid;
            int r = e >> 4, kk = e & 15;
            a_lds[kk][r] = in[(row0 + r) * K + k0 + kk];
        }
#pragma unroll
        for (int i = 0; i < 16; ++i) {
            int e = i * 256 + tid;
            int j = e >> 4, kk = e & 15;
            b_lds[kk][j] = W[j * K + k0 + kk];
        }
        __syncthreads();

#pragma unroll
        for (int kk = 0; kk < 16; ++kk) {
            float4 a0 = *(const float4*)&a_lds[kk][ty * 8];
            float4 a1 = *(const float4*)&a_lds[kk][ty * 8 + 4];
            float4 b0 = *(const float4*)&b_lds[kk][tx * 8];
            float4 b1 = *(const float4*)&b_lds[kk][tx * 8 + 4];
            float av[8] = {a0.x, a0.y, a0.z, a0.w, a1.x, a1.y, a1.z, a1.w};
            float bv[8] = {b0.x, b0.y, b0.z, b0.w, b1.x, b1.y, b1.z, b1.w};
#pragma unroll
            for (int r = 0; r < 8; ++r)
#pragma unroll
                for (int c = 0; c < 8; ++c)
                    acc[r][c] += av[r] * bv[c];
        }
        __syncthreads();
    }

    float bsum[8];
#pragma unroll
    for (int c = 0; c < 8; ++c) {
        int j = tx * 8 + c;
        bsum[c] = bias1[j] + bias2[j];
    }
#pragma unroll
    for (int r = 0; r < 8; ++r) {
        int row = row0 + ty * 8 + r;
        float4 o0 = make_float4(acc[r][0] + bsum[0], acc[r][1] + bsum[1],
                                acc[r][2] + bsum[2], acc[r][3] + bsum[3]);
        float4 o1 = make_float4(acc[r][4] + bsum[4], acc[r][5] + bsum[5],
                                acc[r][6] + bsum[6], acc[r][7] + bsum[7]);
        *(float4*)&out[row * HH + tx * 8]     = o0;
        *(float4*)&out[row * HH + tx * 8 + 4] = o1;
    }
}

// ---------------------------------------------------------------------------
// fast tanh: 1 - 2/(e^{2x}+1), e^{2x} via v_exp_f32 (exp2 with pre-scaled
// arg). 7 VALU ops. |error| ~1e-7 vs libm; clamp keeps exp2 arg in [-26,26].
// ---------------------------------------------------------------------------
__device__ __forceinline__ float fast_tanh(float x)
{
    float xc = fmaxf(-9.0f, fminf(9.0f, x));
    float e  = __builtin_amdgcn_exp2f(xc * 2.8853900817779268f);  // 2*log2(e)
    return fmaf(-2.0f, __builtin_amdgcn_rcpf(e + 1.0f), 1.0f);
}

// fold s across lane-group xor-16 (within each 32-lane half): ds_swizzle,
// BitMode offset (xor<<10)|and = 0x401F.
__device__ __forceinline__ float fold16(float s)
{
    int v = __builtin_amdgcn_ds_swizzle(__float_as_int(s), 0x401F);
    return s + __int_as_float(v);
}

// fold s across lane xor-32: v_permlane32_swap (single VALU instr writing
// both halves); sum of the two results = s[i] + s[i^32] on every lane.
__device__ __forceinline__ float fold32(float s)
{
#if __has_builtin(__builtin_amdgcn_permlane32_swap)
    typedef unsigned uint2v __attribute__((ext_vector_type(2)));
    uint2v r = __builtin_amdgcn_permlane32_swap(__float_as_uint(s), __float_as_uint(s),
                                                false, false);
    return __uint_as_float(r[0]) + __uint_as_float(r[1]);
#else
    return s + __shfl_xor(s, 32, 64);
#endif
}

// ---------------------------------------------------------------------------
// Recurrence v4: h_t = tanh(xp[t] + W_hh @ h_{t-1}), in-place over xp.
// One WG (16 waves, 1024 thr) per batch. Same dataflow as v3 (distributed
// no-atomic reduce, readlane h-broadcast, double-buffered partials, ONE
// barrier/step), with the serial chain and VALU overhead trimmed:
//  - __launch_bounds__(1024,4): 128-VGPR budget so wreg stays in VGPRs.
//  - folds via ds_swizzle(xor16) + v_permlane32_swap(xor32) instead of
//    generic __shfl_xor (saves bpermute addr calc + latency).
//  - exp2-form tanh (7 VALU).
//  - explicit 2-step unroll, precomputed LDS pointers, strength-reduced
//    global pointers.
// Buffer protocol: step reads CUR partials (written last step), writes NXT,
// ONE barrier at end separates write(NXT)@t from read(NXT)@t+1 and
// read(CUR)@t (pre-barrier) from write(CUR)@t+1 (post-barrier).
// ---------------------------------------------------------------------------
constexpr int PS = HH + 4;   // 260: read stride -> 2-way bank alias (free)

struct StepPtrs {
    const float* rdA;   // &pbufA[4g*PS + jr]
    const float* rdB;
    float* wrA;         // &pbufA[w*PS + 4l]
    float* wrB;
};

__device__ __forceinline__ void rnn_step(const float* rd, float* wr,
                                         float*& pw, const float* pr,
                                         float& xg, const float (&wreg)[4][16],
                                         bool lane_lt16)
{
    // (A) prefetch next step's xp (hidden under this step's work)
    float xg2 = *pr;

    // (B) reduce 16 partial sets for my output jr: 4 strided reads + folds
    float s0 = rd[0 * PS], s1 = rd[1 * PS], s2 = rd[2 * PS], s3 = rd[3 * PS];
    float s = (s0 + s1) + (s2 + s3);
    s = fold16(s);
    s = fold32(s);

    // (C) finish: tanh, commit h (lanes 0..15 hold the valid fold result)
    float hv = fast_tanh(s + xg);
    if (lane_lt16) *pw = hv;

    // (D+E) broadcast my wave's h chunk lane-by-lane, fused into the MACs
    float p0 = 0.f, p1 = 0.f, p2 = 0.f, p3 = 0.f;
#pragma unroll
    for (int c = 0; c < 16; ++c) {
        float hcv = __int_as_float(__builtin_amdgcn_readlane(__float_as_int(hv), c));
        p0 = fmaf(wreg[0][c], hcv, p0);
        p1 = fmaf(wreg[1][c], hcv, p1);
        p2 = fmaf(wreg[2][c], hcv, p2);
        p3 = fmaf(wreg[3][c], hcv, p3);
    }

    // (F) one contiguous b128 write of partials into the other buffer
    *(float4*)wr = make_float4(p0, p1, p2, p3);

    __syncthreads();
    xg = xg2;
    pw += HH;
}

__global__ __launch_bounds__(1024, 4) void rnn_recur(float* xp, const float* Whh)
{
    __shared__ float pbufA[16 * PS];
    __shared__ float pbufB[16 * PS];

    const int tid = threadIdx.x;
    const int w   = tid >> 6;            // wave 0..15 -> k-chunk [16w,16w+16)
    const int l   = tid & 63;
    const int g   = l >> 4;              // reduce lane-group 0..3
    const int jr  = 16 * w + (l & 15);   // output index this lane finishes
    const bool lane_lt16 = (l < 16);
    float* xpb = xp + (size_t)blockIdx.x * Tt * HH;

    // weights (one-time): wreg[r][c] = Whh[(4l + r)][16w + c]
    float wreg[4][16];
#pragma unroll
    for (int r = 0; r < 4; ++r) {
        const float4* wp = (const float4*)&Whh[(size_t)(4 * l + r) * HH + 16 * w];
#pragma unroll
        for (int q = 0; q < 4; ++q) {
            float4 v = wp[q];
            wreg[r][4 * q + 0] = v.x;
            wreg[r][4 * q + 1] = v.y;
            wreg[r][4 * q + 2] = v.z;
            wreg[r][4 * q + 3] = v.w;
        }
    }

    const float* rdA = &pbufA[4 * g * PS + jr];
    const float* rdB = &pbufB[4 * g * PS + jr];
    float*       wrA = &pbufA[w * PS + 4 * l];
    float*       wrB = &pbufB[w * PS + 4 * l];

    // prologue: h_{-1} = 0 -> step-0 partials (read from A) are all zero
    *(float4*)wrA = make_float4(0.f, 0.f, 0.f, 0.f);
    float xg = xpb[jr];                  // xp[t=0][jr]
    float* pw = xpb + jr;                // h write ptr (advances by HH/step)
    const float* pr = xpb + HH + jr;     // prefetch ptr for t+1
    __syncthreads();

    // main loop: pairs (t, t+1), prefetch t+1 and t+2; run while t+2 <= Tt-1
#pragma unroll 1
    for (int t = 0; t < Tt - 2; t += 2) {
        rnn_step(rdA, wrB, pw, pr, xg, wreg, lane_lt16); pr += HH;
        rnn_step(rdB, wrA, pw, pr, xg, wreg, lane_lt16); pr += HH;
    }
    // final pair t = Tt-2, Tt-1: prefetch clamps to row Tt-1 (never consumed)
    rnn_step(rdA, wrB, pw, pr, xg, wreg, lane_lt16);
    rnn_step(rdB, wrA, pw, pr, xg, wreg, lane_lt16);
}

// ---------------------------------------------------------------------------
// FC: out[b] = dot(h2[b][T-1][:], W_fc) + b_fc.  One wave per batch.
// ---------------------------------------------------------------------------
__global__ __launch_bounds__(64) void fc_kernel(const float* h2, const float* Wfc,
                                                const float* bfc, float* out)
{
    const int b = blockIdx.x;
    const int l = threadIdx.x;    // 0..63
    const float* hrow = h2 + ((size_t)b * Tt + (Tt - 1)) * HH;
    float4 hv = *(const float4*)&hrow[4 * l];
    float4 wv = *(const float4*)&Wfc[4 * l];
    float p = hv.x * wv.x + hv.y * wv.y + hv.z * wv.z + hv.w * wv.w;
#pragma unroll
    for (int off = 32; off > 0; off >>= 1) p += __shfl_down(p, off, 64);
    if (l == 0) out[b] = p + bfc[0];
}

// ---------------------------------------------------------------------------
extern "C" void kernel_launch(void* const* d_in, const int* in_sizes, int n_in,
                              void* d_out, int out_size, void* d_ws, size_t ws_size,
                              hipStream_t stream)
{
    const float* x     = (const float*)d_in[0];
    const float* W_ih0 = (const float*)d_in[1];
    const float* W_hh0 = (const float*)d_in[2];
    const float* b_ih0 = (const float*)d_in[3];
    const float* b_hh0 = (const float*)d_in[4];
    const float* W_ih1 = (const float*)d_in[5];
    const float* W_hh1 = (const float*)d_in[6];
    const float* b_ih1 = (const float*)d_in[7];
    const float* b_hh1 = (const float*)d_in[8];
    const float* W_fc  = (const float*)d_in[9];
    const float* b_fc  = (const float*)d_in[10];
    float* ws  = (float*)d_ws;                 // B*T*H floats (128 MiB)
    float* out = (float*)d_out;                // 64 floats

    // 1) xp0 = x @ W_ih0^T + b_ih0 + b_hh0
    ih_gemm<INN><<<ROWS / 64, 256, 0, stream>>>(x, W_ih0, b_ih0, b_hh0, ws);
    // 2) layer-0 recurrence (in-place: ws becomes h1 sequence)
    rnn_recur<<<Bb, 1024, 0, stream>>>(ws, W_hh0);
    // 3) xp1 = h1 @ W_ih1^T + b_ih1 + b_hh1   (in-place)
    ih_gemm<HH><<<ROWS / 64, 256, 0, stream>>>(ws, W_ih1, b_ih1, b_hh1, ws);
    // 4) layer-1 recurrence (in-place: ws becomes h2 sequence)
    rnn_recur<<<Bb, 1024, 0, stream>>>(ws, W_hh1);
    // 5) out = h2[:, T-1, :] @ W_fc^T + b_fc
    fc_kernel<<<Bb, 64, 0, stream>>>(ws, W_fc, b_fc, out);
}

// Round 4
// 1744.278 us; speedup vs baseline: 12.9933x; 1.5767x over previous
//
#include <hip/hip_runtime.h>
#include <math.h>

constexpr int Bb  = 64;
constexpr int Tt  = 2048;
constexpr int INN = 128;
constexpr int HH  = 256;
constexpr int ROWS = Bb * Tt;   // 131072
constexpr int CH  = 64;         // pipeline chunk (rows of one batch)
constexpr int NCH = Tt / CH;    // 32 chunks
constexpr int PS  = HH + 4;     // 260: partial-buffer row stride

// Inter-role progress flags (rows completed per batch). Monotonic within one
// kernel execution; re-zeroed by ih_gemm (previous kernel in stream) each run.
__device__ int g_flag0[Bb];     // producer  -> gemm
__device__ int g_flag1[Bb];     // gemm      -> consumer

// ---------------------------------------------------------------------------
// xp0 GEMM: out[row][j] = sum_k x[row][k]*W[j][k] + b1[j] + b2[j], K=128.
// 256 threads, 64x256 tile, 8x8 per thread (unchanged machinery, verified).
// Block 0 additionally zeroes the pipeline flags for this run.
// ---------------------------------------------------------------------------
__global__ __launch_bounds__(256) void ih_gemm(const float* in, const float* W,
                                               const float* bias1, const float* bias2,
                                               float* out)
{
    __shared__ float a_lds[16][68];
    __shared__ float b_lds[16][264];

    const int tid = threadIdx.x;
    if (blockIdx.x == 0 && tid < Bb) { g_flag0[tid] = 0; g_flag1[tid] = 0; }

    const int tx  = tid & 31;
    const int ty  = tid >> 5;
    const int row0 = blockIdx.x * 64;

    float acc[8][8];
#pragma unroll
    for (int r = 0; r < 8; ++r)
#pragma unroll
        for (int c = 0; c < 8; ++c) acc[r][c] = 0.f;

    for (int k0 = 0; k0 < INN; k0 += 16) {
#pragma unroll
        for (int i = 0; i < 4; ++i) {
            int e = i * 256 + tid;
            int r = e >> 4, kk = e & 15;
            a_lds[kk][r] = in[(row0 + r) * INN + k0 + kk];
        }
#pragma unroll
        for (int i = 0; i < 16; ++i) {
            int e = i * 256 + tid;
            int j = e >> 4, kk = e & 15;
            b_lds[kk][j] = W[j * INN + k0 + kk];
        }
        __syncthreads();

#pragma unroll
        for (int kk = 0; kk < 16; ++kk) {
            float4 a0 = *(const float4*)&a_lds[kk][ty * 8];
            float4 a1 = *(const float4*)&a_lds[kk][ty * 8 + 4];
            float4 b0 = *(const float4*)&b_lds[kk][tx * 8];
            float4 b1 = *(const float4*)&b_lds[kk][tx * 8 + 4];
            float av[8] = {a0.x, a0.y, a0.z, a0.w, a1.x, a1.y, a1.z, a1.w};
            float bv[8] = {b0.x, b0.y, b0.z, b0.w, b1.x, b1.y, b1.z, b1.w};
#pragma unroll
            for (int r = 0; r < 8; ++r)
#pragma unroll
                for (int c = 0; c < 8; ++c)
                    acc[r][c] += av[r] * bv[c];
        }
        __syncthreads();
    }

    float bsum[8];
#pragma unroll
    for (int c = 0; c < 8; ++c) {
        int j = tx * 8 + c;
        bsum[c] = bias1[j] + bias2[j];
    }
#pragma unroll
    for (int r = 0; r < 8; ++r) {
        int row = row0 + ty * 8 + r;
        float4 o0 = make_float4(acc[r][0] + bsum[0], acc[r][1] + bsum[1],
                                acc[r][2] + bsum[2], acc[r][3] + bsum[3]);
        float4 o1 = make_float4(acc[r][4] + bsum[4], acc[r][5] + bsum[5],
                                acc[r][6] + bsum[6], acc[r][7] + bsum[7]);
        *(float4*)&out[row * HH + tx * 8]     = o0;
        *(float4*)&out[row * HH + tx * 8 + 4] = o1;
    }
}

// ---------------------------------------------------------------------------
// fast tanh, clamp-free: x->+inf: e=inf, rcp=0 -> 1; x->-inf: e=0 -> -1.
// ---------------------------------------------------------------------------
__device__ __forceinline__ float fast_tanh(float x)
{
    float e = __builtin_amdgcn_exp2f(x * 2.8853900817779268f);  // 2*log2(e)
    return fmaf(-2.0f, __builtin_amdgcn_rcpf(e + 1.0f), 1.0f);
}

__device__ __forceinline__ float fold16(float s)
{
    int v = __builtin_amdgcn_ds_swizzle(__float_as_int(s), 0x401F);  // xor 16
    return s + __int_as_float(v);
}

__device__ __forceinline__ float fold32(float s)
{
#if __has_builtin(__builtin_amdgcn_permlane32_swap)
    typedef unsigned uint2v __attribute__((ext_vector_type(2)));
    uint2v r = __builtin_amdgcn_permlane32_swap(__float_as_uint(s), __float_as_uint(s),
                                                false, false);
    return __uint_as_float(r[0]) + __uint_as_float(r[1]);
#else
    return s + __shfl_xor(s, 32, 64);
#endif
}

// ---------------------------------------------------------------------------
// One recurrence step (v4-verified dataflow): reads partials from rd,
// writes next-step partials to wr, commits h over xp[t] (in-place), ONE
// barrier. xg carries xp[t]; prefetches *pr into xg for the next step.
// ---------------------------------------------------------------------------
__device__ __forceinline__ void rnn_step(const float* rd, float* wr,
                                         float*& pw, const float* pr,
                                         float& xg, const float (&wreg)[4][16],
                                         bool lane_lt16)
{
    float xg2 = *pr;

    float s0 = rd[0 * PS], s1 = rd[1 * PS], s2 = rd[2 * PS], s3 = rd[3 * PS];
    float s = (s0 + s1) + (s2 + s3);
    s = fold16(s);
    s = fold32(s);

    float hv = fast_tanh(s + xg);
    if (lane_lt16) *pw = hv;

    float p0 = 0.f, p1 = 0.f, p2 = 0.f, p3 = 0.f;
#pragma unroll
    for (int c = 0; c < 16; ++c) {
        float hcv = __int_as_float(__builtin_amdgcn_readlane(__float_as_int(hv), c));
        p0 = fmaf(wreg[0][c], hcv, p0);
        p1 = fmaf(wreg[1][c], hcv, p1);
        p2 = fmaf(wreg[2][c], hcv, p2);
        p3 = fmaf(wreg[3][c], hcv, p3);
    }
    *(float4*)wr = make_float4(p0, p1, p2, p3);

    __syncthreads();
    xg = xg2;
    pw += HH;
}

// ---------------------------------------------------------------------------
// Recurrence role (producer: layer 0 / consumer: layer 1), chunked.
// PROD: releases g_flag0[b] after each 64-row chunk of h written.
// !PROD: acquires g_flag1[b] before each chunk; reloads xg fresh after the
//        acquire (the cross-chunk prefetch may have read stale data and is
//        discarded). In-place: h overwrites consumed xp rows.
// Tail: last chunk's final pair clamps the prefetch to row Tt-1 (no OOB).
// ---------------------------------------------------------------------------
template <bool PROD>
__device__ void rnn_role(float* xpb, const float* Whh, float* sh, int b)
{
    float* pbufA = sh;
    float* pbufB = sh + 16 * PS;

    const int tid = threadIdx.x;
    const int w   = tid >> 6;
    const int l   = tid & 63;
    const int g   = l >> 4;
    const int jr  = 16 * w + (l & 15);
    const bool lane_lt16 = (l < 16);

    float wreg[4][16];
#pragma unroll
    for (int r = 0; r < 4; ++r) {
        const float4* wp = (const float4*)&Whh[(size_t)(4 * l + r) * HH + 16 * w];
#pragma unroll
        for (int q = 0; q < 4; ++q) {
            float4 v = wp[q];
            wreg[r][4 * q + 0] = v.x;
            wreg[r][4 * q + 1] = v.y;
            wreg[r][4 * q + 2] = v.z;
            wreg[r][4 * q + 3] = v.w;
        }
    }

    const float* rdA = &pbufA[4 * g * PS + jr];
    const float* rdB = &pbufB[4 * g * PS + jr];
    float*       wrA = &pbufA[w * PS + 4 * l];
    float*       wrB = &pbufB[w * PS + 4 * l];

    *(float4*)wrA = make_float4(0.f, 0.f, 0.f, 0.f);   // h_{-1} = 0
    float xg = PROD ? xpb[jr] : 0.f;    // consumer: overwritten post-acquire
    float* pw = xpb + jr;
    const float* pr = xpb + HH + jr;
    __syncthreads();

#pragma unroll 1
    for (int c = 0; c < NCH; ++c) {
        if (!PROD) {
            // wait for this chunk's xp rows, then fresh-load current xp
            while (__hip_atomic_load(&g_flag1[b], __ATOMIC_ACQUIRE,
                                     __HIP_MEMORY_SCOPE_AGENT) < (c + 1) * CH)
                __builtin_amdgcn_s_sleep(16);
            xg = xpb[(size_t)c * CH * HH + jr];
        }
        const int npairs = (c == NCH - 1) ? (CH / 2 - 1) : (CH / 2);
#pragma unroll 1
        for (int p = 0; p < npairs; ++p) {
            rnn_step(rdA, wrB, pw, pr, xg, wreg, lane_lt16); pr += HH;
            rnn_step(rdB, wrA, pw, pr, xg, wreg, lane_lt16); pr += HH;
        }
        if (c == NCH - 1) {   // final pair: prefetch clamped to row Tt-1
            rnn_step(rdA, wrB, pw, pr, xg, wreg, lane_lt16);
            rnn_step(rdB, wrA, pw, pr, xg, wreg, lane_lt16);
        }
        if (PROD && tid == 0) {
            __threadfence();   // flush h chunk to agent scope (L2 -> MALL)
            __hip_atomic_store(&g_flag0[b], (c + 1) * CH,
                               __ATOMIC_RELEASE, __HIP_MEMORY_SCOPE_AGENT);
        }
    }
}

// ---------------------------------------------------------------------------
// GEMM role: per chunk, xp1 rows = h1 rows @ W_ih1^T + b_ih1 + b_hh1,
// written IN PLACE over the consumed h1 rows. 1024 threads, 64x256 tile,
// 4x4 per thread. Waits g_flag0 per chunk, releases g_flag1 after stores.
// ---------------------------------------------------------------------------
__device__ void gemm_role(float* ws, const float* W,
                          const float* b1, const float* b2, float* sh, int b)
{
    float (*a_lds)[68]  = (float(*)[68])sh;
    float (*b_lds)[264] = (float(*)[264])(sh + 16 * 68);

    const int tid = threadIdx.x;
    const int tx  = tid & 63;    // cols 4tx..4tx+3
    const int ty  = tid >> 6;    // rows 4ty..4ty+3

    float bs[4];
#pragma unroll
    for (int q = 0; q < 4; ++q) {
        int j = tx * 4 + q;
        bs[q] = b1[j] + b2[j];
    }

#pragma unroll 1
    for (int c = 0; c < NCH; ++c) {
        while (__hip_atomic_load(&g_flag0[b], __ATOMIC_ACQUIRE,
                                 __HIP_MEMORY_SCOPE_AGENT) < (c + 1) * CH)
            __builtin_amdgcn_s_sleep(16);

        const size_t row0 = (size_t)b * Tt + (size_t)c * CH;
        float acc[4][4];
#pragma unroll
        for (int r = 0; r < 4; ++r)
#pragma unroll
            for (int q = 0; q < 4; ++q) acc[r][q] = 0.f;

        for (int k0 = 0; k0 < HH; k0 += 16) {
            {   // A tile: 64 rows x 16 k = 1024 elems, 1/thread
                int r = tid >> 4, kk = tid & 15;
                a_lds[kk][r] = ws[(row0 + r) * HH + k0 + kk];
            }
#pragma unroll
            for (int i = 0; i < 4; ++i) {   // B tile: 256x16 = 4096, 4/thread
                int e = i * 1024 + tid;
                int j = e >> 4, kk = e & 15;
                b_lds[kk][j] = W[j * HH + k0 + kk];
            }
            __syncthreads();
#pragma unroll
            for (int kk = 0; kk < 16; ++kk) {
                float4 av = *(const float4*)&a_lds[kk][ty * 4];
                float4 bv = *(const float4*)&b_lds[kk][tx * 4];
                float avs[4] = {av.x, av.y, av.z, av.w};
                float bvs[4] = {bv.x, bv.y, bv.z, bv.w};
#pragma unroll
                for (int r = 0; r < 4; ++r)
#pragma unroll
                    for (int q = 0; q < 4; ++q)
                        acc[r][q] = fmaf(avs[r], bvs[q], acc[r][q]);
            }
            __syncthreads();
        }

#pragma unroll
        for (int r = 0; r < 4; ++r) {
            size_t row = row0 + ty * 4 + r;
            *(float4*)&ws[row * HH + tx * 4] =
                make_float4(acc[r][0] + bs[0], acc[r][1] + bs[1],
                            acc[r][2] + bs[2], acc[r][3] + bs[3]);
        }
        __syncthreads();   // per-wave vmcnt drain: all stores retired
        if (tid == 0) {
            __threadfence();
            __hip_atomic_store(&g_flag1[b], (c + 1) * CH,
                               __ATOMIC_RELEASE, __HIP_MEMORY_SCOPE_AGENT);
        }
    }
}

// ---------------------------------------------------------------------------
// Pipelined fused kernel: blocks 0..63 producer (layer-0 recurrence),
// 64..127 gemm (xp1 tiles), 128..191 consumer (layer-1 recurrence).
// 192 blocks <= 256 CUs: all dispatch at kernel start (producers first in
// blockIdx order); wait graph is a DAG (prod -> gemm -> cons) => no deadlock.
// ---------------------------------------------------------------------------
__global__ __launch_bounds__(1024, 4) void pipeline_kernel(
        float* ws, const float* Whh0, const float* Wih1,
        const float* bih1, const float* bhh1, const float* Whh1)
{
    __shared__ __attribute__((aligned(16))) float sh[2 * 16 * PS];  // 33280 B

    const int role = blockIdx.x >> 6;
    const int b    = blockIdx.x & 63;

    if (role == 0)
        rnn_role<true>(ws + (size_t)b * Tt * HH, Whh0, sh, b);
    else if (role == 1)
        gemm_role(ws, Wih1, bih1, bhh1, sh, b);
    else
        rnn_role<false>(ws + (size_t)b * Tt * HH, Whh1, sh, b);
}

// ---------------------------------------------------------------------------
// FC: out[b] = dot(h2[b][T-1][:], W_fc) + b_fc.  One wave per batch.
// ---------------------------------------------------------------------------
__global__ __launch_bounds__(64) void fc_kernel(const float* h2, const float* Wfc,
                                                const float* bfc, float* out)
{
    const int b = blockIdx.x;
    const int l = threadIdx.x;
    const float* hrow = h2 + ((size_t)b * Tt + (Tt - 1)) * HH;
    float4 hv = *(const float4*)&hrow[4 * l];
    float4 wv = *(const float4*)&Wfc[4 * l];
    float p = hv.x * wv.x + hv.y * wv.y + hv.z * wv.z + hv.w * wv.w;
#pragma unroll
    for (int off = 32; off > 0; off >>= 1) p += __shfl_down(p, off, 64);
    if (l == 0) out[b] = p + bfc[0];
}

// ---------------------------------------------------------------------------
extern "C" void kernel_launch(void* const* d_in, const int* in_sizes, int n_in,
                              void* d_out, int out_size, void* d_ws, size_t ws_size,
                              hipStream_t stream)
{
    const float* x     = (const float*)d_in[0];
    const float* W_ih0 = (const float*)d_in[1];
    const float* W_hh0 = (const float*)d_in[2];
    const float* b_ih0 = (const float*)d_in[3];
    const float* b_hh0 = (const float*)d_in[4];
    const float* W_ih1 = (const float*)d_in[5];
    const float* W_hh1 = (const float*)d_in[6];
    const float* b_ih1 = (const float*)d_in[7];
    const float* b_hh1 = (const float*)d_in[8];
    const float* W_fc  = (const float*)d_in[9];
    const float* b_fc  = (const float*)d_in[10];
    float* ws  = (float*)d_ws;                 // B*T*H floats (128 MiB)
    float* out = (float*)d_out;

    // 1) xp0 = x @ W_ih0^T + b_ih0 + b_hh0  (+ zero pipeline flags)
    ih_gemm<<<ROWS / 64, 256, 0, stream>>>(x, W_ih0, b_ih0, b_hh0, ws);
    // 2) fused pipeline: L0 recurrence -> chunked xp1 GEMM -> L1 recurrence,
    //    all in-place in ws; ws ends as the h2 sequence.
    pipeline_kernel<<<192, 1024, 0, stream>>>(ws, W_hh0, W_ih1, b_ih1, b_hh1, W_hh1);
    // 3) out = h2[:, T-1, :] @ W_fc^T + b_fc
    fc_kernel<<<Bb, 64, 0, stream>>>(ws, W_fc, b_fc, out);
}